// Round 1
// baseline (719.123 us; speedup 1.0000x reference)
//
#include <hip/hip_runtime.h>
#include <cstddef>
#include <cstdint>

// ---------------- problem constants ----------------
#define ALPHA_C 7.7550531393693407f   // -log(0.001/7*3)
constexpr int BB = 2;      // batch
constexpr int LL = 2048;   // seq len
constexpr int DD = 512;    // d_model
constexpr int HH = 8;      // heads
constexpr size_t OUT0     = (size_t)BB * LL * DD;        // 2,097,152 floats (output 0)
constexpr size_t QH_ELEMS = (size_t)BB * HH * LL * 64;   // 2,097,152 floats per projection

typedef __attribute__((ext_vector_type(8))) short bf16x8;
typedef __attribute__((ext_vector_type(4))) float f32x4;

__device__ inline short f2bf(float x) {
  union { float f; unsigned u; } un; un.f = x;
  unsigned r = un.u + 0x7fffu + ((un.u >> 16) & 1u);   // RNE truncate to bf16
  return (short)(r >> 16);
}

// ---------------- K1: fused QKV projection (fp32 SGEMM) ----------------
// grid (24, 64): x -> {q,k,v} x 8 n-tiles of 64; y -> m-tile of 64 (M = B*L = 4096)
// Y[b,h,l,dk] = sum_d X[b,l,d] * W[h*64+dk, d]
__global__ __launch_bounds__(256) void k_proj(
    const float* __restrict__ q, const float* __restrict__ k, const float* __restrict__ v,
    const float* __restrict__ wq, const float* __restrict__ wk, const float* __restrict__ wv,
    float* __restrict__ qh, float* __restrict__ kh, float* __restrict__ vh)
{
  const int bx  = blockIdx.x;
  const int sel = bx >> 3;                 // 0=q,1=k,2=v
  const int n0  = (bx & 7) * 64;           // output-feature tile within [0,512)
  const int m0  = blockIdx.y * 64;
  const float* X = sel == 0 ? q  : (sel == 1 ? k  : v);
  const float* W = sel == 0 ? wq : (sel == 1 ? wk : wv);
  float*       Y = sel == 0 ? qh : (sel == 1 ? kh : vh);

  __shared__ float As[32][68];   // A^T[k][m], pad 68 keeps 16B alignment + spreads banks
  __shared__ float Bs[32][68];   // B^T[k][e]
  const int tid = threadIdx.x;
  const int tr = tid >> 4, tc = tid & 15;
  const int lm = tid >> 2, lk0 = tid & 3;

  float acc[4][4] = {};
  for (int k0 = 0; k0 < 512; k0 += 32) {
    #pragma unroll
    for (int it = 0; it < 2; ++it) {
      int kv = lk0 + 4 * it;               // 0..7
      float4 a = *(const float4*)&X[(size_t)(m0 + lm) * 512 + k0 + kv * 4];
      As[kv*4+0][lm] = a.x; As[kv*4+1][lm] = a.y; As[kv*4+2][lm] = a.z; As[kv*4+3][lm] = a.w;
      float4 b = *(const float4*)&W[(size_t)(n0 + lm) * 512 + k0 + kv * 4];
      Bs[kv*4+0][lm] = b.x; Bs[kv*4+1][lm] = b.y; Bs[kv*4+2][lm] = b.z; Bs[kv*4+3][lm] = b.w;
    }
    __syncthreads();
    #pragma unroll 8
    for (int kk = 0; kk < 32; ++kk) {
      float4 av = *(const float4*)&As[kk][tr * 4];
      float4 bv = *(const float4*)&Bs[kk][tc * 4];
      acc[0][0] += av.x*bv.x; acc[0][1] += av.x*bv.y; acc[0][2] += av.x*bv.z; acc[0][3] += av.x*bv.w;
      acc[1][0] += av.y*bv.x; acc[1][1] += av.y*bv.y; acc[1][2] += av.y*bv.z; acc[1][3] += av.y*bv.w;
      acc[2][0] += av.z*bv.x; acc[2][1] += av.z*bv.y; acc[2][2] += av.z*bv.z; acc[2][3] += av.z*bv.w;
      acc[3][0] += av.w*bv.x; acc[3][1] += av.w*bv.y; acc[3][2] += av.w*bv.z; acc[3][3] += av.w*bv.w;
    }
    __syncthreads();
  }
  const int e = n0 + tc * 4;               // 4 contiguous features, same head (64-aligned tiles)
  const int h = e >> 6, dk = e & 63;
  #pragma unroll
  for (int r = 0; r < 4; ++r) {
    int m = m0 + tr * 4 + r;
    int b = m >> 11, l = m & 2047;
    float4 o; o.x = acc[r][0]; o.y = acc[r][1]; o.z = acc[r][2]; o.w = acc[r][3];
    *(float4*)&Y[((size_t)(b * HH + h) * LL + l) * 64 + dk] = o;
  }
}

// ---------------- K2: attention logits eld = -alpha*(j-i)*(q.k/8) (fp32 SGEMM) ---------
// grid (32, 32, 16): x=j-tile, y=i-tile, z=bh. K=64. Writes into d_out pooled region.
__global__ __launch_bounds__(256) void k_attn_logits(
    const float* __restrict__ qh, const float* __restrict__ kh, float* __restrict__ eld)
{
  const int j0 = blockIdx.x * 64;
  const int i0 = blockIdx.y * 64;
  const int bh = blockIdx.z;
  const float* Qb = qh + (size_t)bh * LL * 64;
  const float* Kb = kh + (size_t)bh * LL * 64;
  float*       Ob = eld + (size_t)bh * LL * LL;

  __shared__ float As[64][68];
  __shared__ float Bs[64][68];
  const int tid = threadIdx.x;
  const int tr = tid >> 4, tc = tid & 15;
  const int lm = tid >> 2, lk0 = tid & 3;

  #pragma unroll
  for (int it = 0; it < 4; ++it) {
    int kv = lk0 + 4 * it;                 // 0..15
    float4 a = *(const float4*)&Qb[(size_t)(i0 + lm) * 64 + kv * 4];
    As[kv*4+0][lm] = a.x; As[kv*4+1][lm] = a.y; As[kv*4+2][lm] = a.z; As[kv*4+3][lm] = a.w;
    float4 b = *(const float4*)&Kb[(size_t)(j0 + lm) * 64 + kv * 4];
    Bs[kv*4+0][lm] = b.x; Bs[kv*4+1][lm] = b.y; Bs[kv*4+2][lm] = b.z; Bs[kv*4+3][lm] = b.w;
  }
  __syncthreads();

  float acc[4][4] = {};
  #pragma unroll 8
  for (int kk = 0; kk < 64; ++kk) {
    float4 av = *(const float4*)&As[kk][tr * 4];
    float4 bv = *(const float4*)&Bs[kk][tc * 4];
    acc[0][0] += av.x*bv.x; acc[0][1] += av.x*bv.y; acc[0][2] += av.x*bv.z; acc[0][3] += av.x*bv.w;
    acc[1][0] += av.y*bv.x; acc[1][1] += av.y*bv.y; acc[1][2] += av.y*bv.z; acc[1][3] += av.y*bv.w;
    acc[2][0] += av.z*bv.x; acc[2][1] += av.z*bv.y; acc[2][2] += av.z*bv.z; acc[2][3] += av.z*bv.w;
    acc[3][0] += av.w*bv.x; acc[3][1] += av.w*bv.y; acc[3][2] += av.w*bv.z; acc[3][3] += av.w*bv.w;
  }

  #pragma unroll
  for (int r = 0; r < 4; ++r) {
    int i = i0 + tr * 4 + r;
    float4 o;
    {
      int j = j0 + tc * 4;
      o.x = -ALPHA_C * (float)(j + 0 - i) * (acc[r][0] * 0.125f);
      o.y = -ALPHA_C * (float)(j + 1 - i) * (acc[r][1] * 0.125f);
      o.z = -ALPHA_C * (float)(j + 2 - i) * (acc[r][2] * 0.125f);
      o.w = -ALPHA_C * (float)(j + 3 - i) * (acc[r][3] * 0.125f);
    }
    *(float4*)&Ob[(size_t)i * LL + j0 + tc * 4] = o;
  }
}

// ---------------- K3: softmax + 3-tap avg-pool, in place ----------------
// grid (32768): one block per (bh, i) row. Pool needs only same-row neighbors -> in-place safe.
__global__ __launch_bounds__(256) void k_softmax_pool(float* __restrict__ p)
{
  float* P = p + (size_t)blockIdx.x * LL;
  __shared__ float prow[LL];
  __shared__ float red[256];
  const int tid = threadIdx.x;

  float v[8];
  float mx = -3.0e38f;
  #pragma unroll
  for (int s = 0; s < 8; ++s) { v[s] = P[tid + 256 * s]; mx = fmaxf(mx, v[s]); }
  red[tid] = mx; __syncthreads();
  for (int off = 128; off > 0; off >>= 1) {
    if (tid < off) red[tid] = fmaxf(red[tid], red[tid + off]);
    __syncthreads();
  }
  mx = red[0]; __syncthreads();

  float sum = 0.f;
  #pragma unroll
  for (int s = 0; s < 8; ++s) { v[s] = __expf(v[s] - mx); sum += v[s]; }
  red[tid] = sum; __syncthreads();
  for (int off = 128; off > 0; off >>= 1) {
    if (tid < off) red[tid] += red[tid + off];
    __syncthreads();
  }
  const float inv = 1.0f / red[0];

  #pragma unroll
  for (int s = 0; s < 8; ++s) prow[tid + 256 * s] = v[s] * inv;
  __syncthreads();

  #pragma unroll
  for (int s = 0; s < 8; ++s) {
    int j = tid + 256 * s;
    float lft = (j > 0)      ? prow[j - 1] : 0.f;
    float rgt = (j < LL - 1) ? prow[j + 1] : 0.f;
    P[j] = (lft + prow[j] + rgt) * (1.0f / 3.0f);
  }
}

// ---------------- K4: out_h = pooled @ vh  (bf16 MFMA) ----------------
// grid (32, 16): x=i-tile of 64, y=bh. M=2048, N=64, K=2048.
__global__ __launch_bounds__(256) void k_pv(
    const float* __restrict__ pooled, const float* __restrict__ vh, float* __restrict__ outh)
{
  const int i0 = blockIdx.x * 64;
  const int bh = blockIdx.y;
  const int b = bh >> 3, h = bh & 7;
  const float* P = pooled + (size_t)bh * LL * LL;
  const float* V = vh     + (size_t)bh * LL * 64;

  __shared__ short Asm[64 * 64];   // A[i][k]  bf16
  __shared__ short Bsm[64 * 64];   // B^T[d][k] bf16
  const int tid = threadIdx.x;
  const int lane = tid & 63, w = tid >> 6;

  f32x4 acc[4];
  #pragma unroll
  for (int t = 0; t < 4; ++t)
    #pragma unroll
    for (int e = 0; e < 4; ++e) acc[t][e] = 0.f;

  const int am = tid >> 2, ak = tid & 3;     // A-stage mapping
  const int bjq = tid >> 4, bd = tid & 15;   // B-stage mapping

  for (int k0 = 0; k0 < LL; k0 += 64) {
    #pragma unroll
    for (int it = 0; it < 4; ++it) {
      int kv = ak + 4 * it;                  // 0..15
      float4 a = *(const float4*)&P[(size_t)(i0 + am) * LL + k0 + kv * 4];
      short s0 = f2bf(a.x), s1 = f2bf(a.y), s2 = f2bf(a.z), s3 = f2bf(a.w);
      short* dst = &Asm[am * 64 + kv * 4];
      dst[0] = s0; dst[1] = s1; dst[2] = s2; dst[3] = s3;
    }
    #pragma unroll
    for (int it = 0; it < 4; ++it) {
      int j = bjq + 16 * it;                 // 0..63 (k within chunk)
      float4 a = *(const float4*)&V[(size_t)(k0 + j) * 64 + bd * 4];
      Bsm[(bd * 4 + 0) * 64 + j] = f2bf(a.x);
      Bsm[(bd * 4 + 1) * 64 + j] = f2bf(a.y);
      Bsm[(bd * 4 + 2) * 64 + j] = f2bf(a.z);
      Bsm[(bd * 4 + 3) * 64 + j] = f2bf(a.w);
    }
    __syncthreads();
    #pragma unroll
    for (int sub = 0; sub < 64; sub += 32) {
      int krow = sub + ((lane >> 4) << 3);
      bf16x8 af = *(const bf16x8*)&Asm[(w * 16 + (lane & 15)) * 64 + krow];
      #pragma unroll
      for (int t = 0; t < 4; ++t) {
        bf16x8 bfv = *(const bf16x8*)&Bsm[(t * 16 + (lane & 15)) * 64 + krow];
        acc[t] = __builtin_amdgcn_mfma_f32_16x16x32_bf16(af, bfv, acc[t], 0, 0, 0);
      }
    }
    __syncthreads();
  }
  const int q4 = lane >> 4, col = lane & 15;
  #pragma unroll
  for (int t = 0; t < 4; ++t)
    #pragma unroll
    for (int r = 0; r < 4; ++r) {
      int i = i0 + w * 16 + q4 * 4 + r;
      int d = t * 16 + col;
      outh[((size_t)b * LL + i) * 512 + h * 64 + d] = acc[t][r];
    }
}

// ---------------- K5: fc = out_h @ w_fc^T  (bf16 MFMA) ----------------
// grid (8, 64): x=n-tile, y=m-tile. M=4096, N=512, K=512. w_fc is [n][k] already.
__global__ __launch_bounds__(256) void k_fc(
    const float* __restrict__ outh, const float* __restrict__ wfc, float* __restrict__ fcout)
{
  const int n0 = blockIdx.x * 64;
  const int m0 = blockIdx.y * 64;
  __shared__ short Asm[64 * 64];
  __shared__ short Bsm[64 * 64];
  const int tid = threadIdx.x;
  const int lane = tid & 63, w = tid >> 6;

  f32x4 acc[4];
  #pragma unroll
  for (int t = 0; t < 4; ++t)
    #pragma unroll
    for (int e = 0; e < 4; ++e) acc[t][e] = 0.f;

  const int am = tid >> 2, ak = tid & 3;
  for (int k0 = 0; k0 < 512; k0 += 64) {
    #pragma unroll
    for (int it = 0; it < 4; ++it) {
      int kv = ak + 4 * it;
      float4 a = *(const float4*)&outh[(size_t)(m0 + am) * 512 + k0 + kv * 4];
      short* da = &Asm[am * 64 + kv * 4];
      da[0] = f2bf(a.x); da[1] = f2bf(a.y); da[2] = f2bf(a.z); da[3] = f2bf(a.w);
      float4 b = *(const float4*)&wfc[(size_t)(n0 + am) * 512 + k0 + kv * 4];
      short* db = &Bsm[am * 64 + kv * 4];
      db[0] = f2bf(b.x); db[1] = f2bf(b.y); db[2] = f2bf(b.z); db[3] = f2bf(b.w);
    }
    __syncthreads();
    #pragma unroll
    for (int sub = 0; sub < 64; sub += 32) {
      int krow = sub + ((lane >> 4) << 3);
      bf16x8 af = *(const bf16x8*)&Asm[(w * 16 + (lane & 15)) * 64 + krow];
      #pragma unroll
      for (int t = 0; t < 4; ++t) {
        bf16x8 bfv = *(const bf16x8*)&Bsm[(t * 16 + (lane & 15)) * 64 + krow];
        acc[t] = __builtin_amdgcn_mfma_f32_16x16x32_bf16(af, bfv, acc[t], 0, 0, 0);
      }
    }
    __syncthreads();
  }
  const int q4 = lane >> 4, col = lane & 15;
  #pragma unroll
  for (int t = 0; t < 4; ++t)
    #pragma unroll
    for (int r = 0; r < 4; ++r) {
      int m = m0 + w * 16 + q4 * 4 + r;
      fcout[(size_t)m * 512 + n0 + t * 16 + col] = acc[t][r];
    }
}

// ---------------- K6: residual + LayerNorm ----------------
// grid (4096): one block per (b,l) row of 512.
__global__ __launch_bounds__(256) void k_ln(
    const float* __restrict__ fcout, const float* __restrict__ resid,
    const float* __restrict__ gamma, const float* __restrict__ beta,
    float* __restrict__ out)
{
  const size_t row = blockIdx.x;
  const int tid = threadIdx.x;
  __shared__ float red[256];

  float x0 = fcout[row * 512 + tid]       + resid[row * 512 + tid];
  float x1 = fcout[row * 512 + 256 + tid] + resid[row * 512 + 256 + tid];

  red[tid] = x0 + x1; __syncthreads();
  for (int off = 128; off > 0; off >>= 1) {
    if (tid < off) red[tid] += red[tid + off];
    __syncthreads();
  }
  const float mu = red[0] * (1.0f / 512.0f); __syncthreads();

  float d0 = x0 - mu, d1 = x1 - mu;
  red[tid] = d0 * d0 + d1 * d1; __syncthreads();
  for (int off = 128; off > 0; off >>= 1) {
    if (tid < off) red[tid] += red[tid + off];
    __syncthreads();
  }
  const float var = red[0] * (1.0f / 512.0f);
  const float rstd = 1.0f / sqrtf(var + 1e-6f);

  out[row * 512 + tid]       = d0 * rstd * gamma[tid]       + beta[tid];
  out[row * 512 + 256 + tid] = d1 * rstd * gamma[tid + 256] + beta[tid + 256];
}

// ---------------- launch ----------------
extern "C" void kernel_launch(void* const* d_in, const int* in_sizes, int n_in,
                              void* d_out, int out_size, void* d_ws, size_t ws_size,
                              hipStream_t stream)
{
  const float* q     = (const float*)d_in[0];
  const float* k     = (const float*)d_in[1];
  const float* v     = (const float*)d_in[2];
  const float* wq    = (const float*)d_in[3];
  const float* wk    = (const float*)d_in[4];
  const float* wv    = (const float*)d_in[5];
  const float* wfc   = (const float*)d_in[6];
  const float* gamma = (const float*)d_in[7];
  const float* beta  = (const float*)d_in[8];

  float* out    = (float*)d_out;
  float* pooled = out + OUT0;                 // output 1 region; also used as logits scratch

  float* wsf  = (float*)d_ws;                 // needs 4 * 8 MB = 32 MB
  float* qh   = wsf;
  float* kh   = wsf + QH_ELEMS;
  float* vh   = wsf + 2 * QH_ELEMS;
  float* outh = wsf + 3 * QH_ELEMS;
  float* fcout = qh;                          // qh/kh dead after K2 -> reuse

  k_proj        <<<dim3(24, 64),     256, 0, stream>>>(q, k, v, wq, wk, wv, qh, kh, vh);
  k_attn_logits <<<dim3(32, 32, 16), 256, 0, stream>>>(qh, kh, pooled);
  k_softmax_pool<<<dim3(32768),      256, 0, stream>>>(pooled);
  k_pv          <<<dim3(32, 16),     256, 0, stream>>>(pooled, vh, outh);
  k_fc          <<<dim3(8, 64),      256, 0, stream>>>(outh, wfc, fcout);
  k_ln          <<<dim3(4096),       256, 0, stream>>>(fcout, q, gamma, beta, out);
}